// Round 3
// baseline (857.671 us; speedup 1.0000x reference)
//
#include <hip/hip_runtime.h>
#include <hip/hip_cooperative_groups.h>
#include <hip/hip_bf16.h>
#include <stdint.h>

#define N_NODES 50000
#define N_EDGES 200000
#define NODE_F 64
#define EDGE_F 16
#define HID 32
#define LAT 16
#define W2A_L 33792 // per-layer w2a elements: 33 k-steps * 2 m-tiles * 64 lanes * 8
#define SCAN_BLOCKS 196   // 196*256 = 50176 >= 50000
#define NTILES 782        // (N_EDGES+255)/256
#define FUSED_BLOCKS 512
#define FUSED_THREADS (FUSED_BLOCKS*256)

namespace cg = cooperative_groups;

typedef __attribute__((ext_vector_type(8))) short short8;   // 8 bf16 = 4 VGPR
typedef __attribute__((ext_vector_type(4))) float f32x4;
typedef __attribute__((ext_vector_type(2))) float f32x2;

static __device__ __forceinline__ unsigned short bfbits(float f) {
  union { __hip_bfloat16 h; unsigned short s; } c; c.h = __float2bfloat16(f); return c.s;
}
// Truncation pack: 1x v_perm_b32. lo16 = top of bits(v.x), hi16 = top of bits(v.y).
static __device__ __forceinline__ unsigned pkt(f32x2 v) {
  return __builtin_amdgcn_perm(__float_as_uint(v.y), __float_as_uint(v.x), 0x07060302u);
}
union AFrag { short8 v; unsigned u[4]; };

// ---------------- shared phase bodies (used by both paths) ----------------

// w2a[l][k][mt][lane][j] = A-frag element A[m = mt*16 + (lane&15)][kk = (lane>>4)*8 + j]
//   where A[m][h] = w2[k][h*32 + m]  (k<32), or b2[h*32 + m] (k==32 bias fold).
__device__ __forceinline__ void dev_prep_item(int g,
    const float* ew2, const float* eb2, const float* ew1,
    unsigned short* w2a, unsigned short* w1p, int* deg) {
  if (g < 3*W2A_L) {
    int l = g / W2A_L;
    int r = g % W2A_L;
    int k = r >> 10;            // 0..32
    int r2 = r & 1023;
    int mt = r2 >> 9;           // 0..1
    int ln = (r2 >> 3) & 63;
    int j  = r2 & 7;
    int h  = (ln >> 4)*8 + j;   // 0..31
    int m  = mt*16 + (ln & 15); // 0..31
    float v = (k < 32) ? ew2[(size_t)l*32768 + k*1024 + h*32 + m]
                       : eb2[(size_t)l*1024 + h*32 + m];
    w2a[g] = bfbits(v);
  }
  if (g < N_NODES) deg[g] = 0;
  // w1p[l][nt][lane][j] = B-frag element B[k=(lane>>4)*8+j][n=nt*16+(lane&15)]
  if (g < 3*2*64*8) {
    int l2 = g >> 10;
    int r3 = g & 1023;
    int nt = r3 >> 9;
    int ln2 = (r3 >> 3) & 63;
    int j2  = r3 & 7;
    int kgr = ln2 >> 4;
    float w = (kgr < 2) ? ew1[(size_t)l2*512 + (kgr*8 + j2)*32 + nt*16 + (ln2 & 15)] : 0.f;
    w1p[g] = bfbits(w);
  }
}

__device__ __forceinline__ void dev_lin_item(int t, const float* x,
    const float* Ws, const float* bs, float* h) {
  int n = t >> 5, o = t & 31;
  const float4* xp = (const float4*)(x + (size_t)n*NODE_F);
  float acc = bs[o];
  #pragma unroll
  for (int j = 0; j < NODE_F/4; j++) {
    float4 v = xp[j];
    acc = fmaf(v.x, Ws[(4*j+0)*HID+o], acc);
    acc = fmaf(v.y, Ws[(4*j+1)*HID+o], acc);
    acc = fmaf(v.z, Ws[(4*j+2)*HID+o], acc);
    acc = fmaf(v.w, Ws[(4*j+3)*HID+o], acc);
  }
  h[t] = fmaxf(acc, 0.f);
}

__device__ __forceinline__ void dev_hist_item(int t, const int* ei, int* deg) {
  int d = ei[N_EDGES + t];
  d = min(max(d, 0), N_NODES-1);
  atomicAdd(&deg[d], 1);
}

__device__ __forceinline__ void dev_scan1(int b, int tid, int* s,
    const int* deg, int* off, int* bsum) {
  int t = b*256 + tid;
  int d = (t < N_NODES) ? deg[t] : 0;
  s[tid] = d; __syncthreads();
  int v = d;
  #pragma unroll
  for (int ofs = 1; ofs < 256; ofs <<= 1) {
    int w = (tid >= ofs) ? s[tid-ofs] : 0;
    __syncthreads();
    v += w; s[tid] = v;
    __syncthreads();
  }
  if (t < N_NODES) off[t] = v - d;
  if (tid == 255) bsum[b] = v;
}

__device__ __forceinline__ void dev_scan23(int b, int tid, int* sPref,
    int* off, const int* bsum, int* cursor) {
  if (tid < 64) {
    int acc = 0;
    for (int i = tid; i < b; i += 64) acc += bsum[i];
    #pragma unroll
    for (int o = 32; o; o >>= 1) acc += __shfl_down(acc, o);
    if (tid == 0) sPref[0] = acc;
  }
  __syncthreads();
  int pref = sPref[0];
  int t = b*256 + tid;
  if (t < N_NODES) {
    off[t] += pref;
    cursor[t] = 0;
  }
  if (t == 0) off[N_NODES] = N_EDGES;
}

__device__ __forceinline__ void dev_scatter_item(int t, const int* ei,
    const int* off, int* cursor, int* csrs, int* csre, int* csrd) {
  int d = ei[N_EDGES + t];
  d = min(max(d, 0), N_NODES-1);
  int s = ei[t];
  s = min(max(s, 0), N_NODES-1);
  int pos = off[d] + atomicAdd(&cursor[d], 1);
  csrs[pos] = s;
  csre[pos] = t;
  csrd[pos] = d;
}

// Fused msg + CSR aggregation for one 256-edge tile. Identical logic to R2's
// k_msgagg body; tile index passed in so the persistent kernel can loop.
__device__ __forceinline__ void dev_msgagg_tile(
    float* sHE, int* sSRC, int* sEID, int tile, int tid,
    const float* hin, const float* ea,
    const unsigned short* w1pl, const float* b1,
    const unsigned short* w2al,
    const int* csr_src, const int* csr_eid, const int* csr_dst,
    const int* off, float* agg) {
  const int be  = tile*256;
  const int wv   = tid >> 6;          // wave 0..3
  const int lane = tid & 63;
  const int nn   = lane & 15;
  const int quad = lane >> 4;
  const int wbase = wv*64;            // this wave's 64 edges (local CSR positions)

  // per-wave staging of src/eid + bias K-row (all lanes)
  {
    int el = wbase + lane;
    int pos = min(be + el, N_EDGES-1);
    sSRC[el] = csr_src[pos];
    sEID[el] = csr_eid[pos];
    sHE[el*33 + 32] = 1.0f;
  }

  // --- he via MFMA: 4 M-tiles x 2 N-halves (wave-internal) ---
  {
    short8 wb0 = *(const short8*)(w1pl + lane*8);         // nt=0
    short8 wb1 = *(const short8*)(w1pl + 512 + lane*8);   // nt=1
    f32x4 z = {0.f,0.f,0.f,0.f};
    float bv0 = b1[nn], bv1 = b1[nn + 16];
    #pragma unroll
    for (int t = 0; t < 4; t++) {
      AFrag a;
      if (quad < 2) {
        int e = sEID[wbase + t*16 + nn];
        const float4* p = (const float4*)(ea + (size_t)e*EDGE_F + quad*8);
        float4 u = p[0], v = p[1];
        a.u[0] = pkt(f32x2{u.x,u.y}); a.u[1] = pkt(f32x2{u.z,u.w});
        a.u[2] = pkt(f32x2{v.x,v.y}); a.u[3] = pkt(f32x2{v.z,v.w});
      } else {
        #pragma unroll
        for (int i = 0; i < 4; i++) a.u[i] = 0u;
      }
      f32x4 h0 = __builtin_amdgcn_mfma_f32_16x16x32_bf16(a.v, wb0, z, 0, 0, 0);
      f32x4 h1 = __builtin_amdgcn_mfma_f32_16x16x32_bf16(a.v, wb1, z, 0, 0, 0);
      #pragma unroll
      for (int r = 0; r < 4; r++) {
        int ro = (wbase + t*16 + quad*4 + r)*33;
        sHE[ro + nn]      = fmaxf(h0[r] + bv0, 0.f);
        sHE[ro + 16 + nn] = fmaxf(h1[r] + bv1, 0.f);
      }
    }
  }
  // no barrier: all sHE producer/consumer pairs so far are wave-internal

  // B-frags: x^T per tile, packed ONCE (lane: edge=nn, k=h=quad*8+j)
  short8 bx[4];
  #pragma unroll
  for (int t = 0; t < 4; t++) {
    int si = sSRC[wbase + t*16 + nn];
    const float4* p = (const float4*)(hin + (size_t)si*HID + quad*8);
    float4 a = p[0], b = p[1];
    AFrag f;
    f.u[0] = pkt(f32x2{a.x,a.y}); f.u[1] = pkt(f32x2{a.z,a.w});
    f.u[2] = pkt(f32x2{b.x,b.y}); f.u[3] = pkt(f32x2{b.z,b.w});
    bx[t] = f.v;
  }

  f32x4 c0[4], c1[4];
  #pragma unroll
  for (int t = 0; t < 4; t++) { c0[t] = f32x4{0.f,0.f,0.f,0.f}; c1[t] = c0[t]; }
  const f32x4 zz = {0.f,0.f,0.f,0.f};

  const unsigned short* ap = w2al + (unsigned)lane*8;   // [k][mt][lane][8]
  const float* heR[4];
  #pragma unroll
  for (int t = 0; t < 4; t++) heR[t] = sHE + (wbase + t*16 + nn)*33;

  // depth-3 pipeline slots: A-frags (W_k^T, both M-tiles) + he scalars
  short8 sa0[3], sa1[3];
  float  sh[3][4];
  #pragma unroll
  for (int j = 0; j < 3; j++) {
    sa0[j] = *(const short8*)(ap + j*1024);
    sa1[j] = *(const short8*)(ap + j*1024 + 512);
    #pragma unroll
    for (int t = 0; t < 4; t++) sh[j][t] = heR[t][j];
  }

  #pragma unroll 1
  for (int base = 0; base < 30; base += 3) {
    #pragma unroll
    for (int j = 0; j < 3; j++) {
      const int kk = base + j;
      short8 a0 = sa0[j], a1 = sa1[j];
      #pragma unroll
      for (int t = 0; t < 4; t++) {
        f32x4 u0 = __builtin_amdgcn_mfma_f32_16x16x32_bf16(a0, bx[t], zz, 0, 0, 0);
        f32x4 u1 = __builtin_amdgcn_mfma_f32_16x16x32_bf16(a1, bx[t], zz, 0, 0, 0);
        float hk = sh[j][t];
        #pragma unroll
        for (int r = 0; r < 4; r++) {
          c0[t][r] = fmaf(hk, u0[r], c0[t][r]);
          c1[t][r] = fmaf(hk, u1[r], c1[t][r]);
        }
      }
      sa0[j] = *(const short8*)(ap + (kk+3)*1024);
      sa1[j] = *(const short8*)(ap + (kk+3)*1024 + 512);
      #pragma unroll
      for (int t = 0; t < 4; t++) sh[j][t] = heR[t][kk+3];
    }
  }
  #pragma unroll
  for (int j = 0; j < 3; j++) {
    short8 a0 = sa0[j], a1 = sa1[j];
    #pragma unroll
    for (int t = 0; t < 4; t++) {
      f32x4 u0 = __builtin_amdgcn_mfma_f32_16x16x32_bf16(a0, bx[t], zz, 0, 0, 0);
      f32x4 u1 = __builtin_amdgcn_mfma_f32_16x16x32_bf16(a1, bx[t], zz, 0, 0, 0);
      float hk = sh[j][t];
      #pragma unroll
      for (int r = 0; r < 4; r++) {
        c0[t][r] = fmaf(hk, u0[r], c0[t][r]);
        c1[t][r] = fmaf(hk, u1[r], c1[t][r]);
      }
    }
  }

  // msg -> LDS, aliasing this wave's own sHE rows (wave-internal WAR)
  #pragma unroll
  for (int t = 0; t < 4; t++) {
    int ro = (wbase + t*16 + nn)*33 + quad*4;
    sHE[ro + 0]  = c0[t][0]; sHE[ro + 1]  = c0[t][1];
    sHE[ro + 2]  = c0[t][2]; sHE[ro + 3]  = c0[t][3];
    sHE[ro + 16] = c1[t][0]; sHE[ro + 17] = c1[t][1];
    sHE[ro + 18] = c1[t][2]; sHE[ro + 19] = c1[t][3];
  }
  __syncthreads();

  // block-level CSR-run aggregation from the LDS msg tile
  const int s    = be;
  const int wend = s + 256;
  const int nF = csr_dst[min(s,       N_EDGES-1)];
  const int nL = csr_dst[min(s + 255, N_EDGES-1)];
  for (int basei = 0; basei <= nL - nF; basei += 32) {
    int idx = basei + (tid >> 3);
    int n = nF + idx;
    if (n <= nL) {
      int oc = tid & 7;
      int s0 = off[n], s1 = off[n+1];
      int lo = max(s0, s) - s;
      int hi = min(s1, wend) - s;
      float a0 = 0.f, a1 = 0.f, a2 = 0.f, a3 = 0.f;
      for (int j = lo; j < hi; j++) {
        const float* row = sHE + j*33 + oc*4;
        a0 += row[0]; a1 += row[1]; a2 += row[2]; a3 += row[3];
      }
      float* dst = agg + (size_t)n*HID + oc*4;
      if (s0 >= s && s1 <= wend) {
        *(float4*)dst = make_float4(a0, a1, a2, a3);
      } else {
        atomicAdd(dst + 0, a0); atomicAdd(dst + 1, a1);
        atomicAdd(dst + 2, a2); atomicAdd(dst + 3, a3);
      }
    }
  }
}

__device__ __forceinline__ void dev_root_item(int t, float* agg, const int* off,
    const float* hin, const float* rws, const float* rbs, float* hout) {
  int n = t >> 3, oc = t & 7;
  float4* ap = (float4*)(agg + (size_t)n*HID);
  float4 av = ap[oc];
  float inv = 1.f / fmaxf((float)(off[n+1] - off[n]), 1.f);
  float a0 = fmaf(av.x, inv, rbs[oc*4+0]);
  float a1 = fmaf(av.y, inv, rbs[oc*4+1]);
  float a2 = fmaf(av.z, inv, rbs[oc*4+2]);
  float a3 = fmaf(av.w, inv, rbs[oc*4+3]);
  const float4* hp = (const float4*)(hin + (size_t)n*HID);
  #pragma unroll
  for (int jq = 0; jq < 8; jq++) {
    float4 hv = hp[jq];
    #pragma unroll
    for (int c = 0; c < 4; c++) {
      int j = jq*4 + c;
      float h = (c==0)?hv.x:(c==1)?hv.y:(c==2)?hv.z:hv.w;
      const float4* rp = (const float4*)(rws + j*HID + oc*4);
      float4 r = rp[0];
      a0 = fmaf(h, r.x, a0);
      a1 = fmaf(h, r.y, a1);
      a2 = fmaf(h, r.z, a2);
      a3 = fmaf(h, r.w, a3);
    }
  }
  ((float4*)(hout + (size_t)n*HID))[oc] =
      make_float4(fmaxf(a0,0.f), fmaxf(a1,0.f), fmaxf(a2,0.f), fmaxf(a3,0.f));
  ap[oc] = make_float4(0.f, 0.f, 0.f, 0.f);   // ready for next layer
}

__device__ __forceinline__ void dev_decoder_node(int n,
    const float* agg, const int* off, const float* h,
    const float* rws, const float* rbs,
    const float* lows, const float* lobs,
    const float* d1s, const float* d1bs,
    const float* d2s, const float* d2bs,
    float* out) {
  float hv[HID], av[HID];
  const float4* hp = (const float4*)(h + (size_t)n*HID);
  const float4* ap = (const float4*)(agg + (size_t)n*HID);
  #pragma unroll
  for (int i = 0; i < HID/4; i++) {
    float4 v = hp[i]; hv[4*i]=v.x; hv[4*i+1]=v.y; hv[4*i+2]=v.z; hv[4*i+3]=v.w;
    float4 a = ap[i]; av[4*i]=a.x; av[4*i+1]=a.y; av[4*i+2]=a.z; av[4*i+3]=a.w;
  }
  float inv = 1.f / fmaxf((float)(off[n+1] - off[n]), 1.f);
  float hr[HID];
  #pragma unroll 4
  for (int o = 0; o < HID; o++) {
    float a = fmaf(av[o], inv, rbs[o]);
    #pragma unroll
    for (int j = 0; j < HID; j++) a = fmaf(hv[j], rws[j*HID+o], a);
    hr[o] = fmaxf(a, 0.f);
  }
  float z[LAT];
  #pragma unroll
  for (int o = 0; o < LAT; o++) {
    float a = lobs[o];
    #pragma unroll
    for (int j = 0; j < HID; j++) a = fmaf(hr[j], lows[j*LAT+o], a);
    z[o] = a;
  }
  float d[HID];
  #pragma unroll
  for (int o = 0; o < HID; o++) {
    float a = d1bs[o];
    #pragma unroll
    for (int j = 0; j < LAT; j++) a = fmaf(z[j], d1s[j*HID+o], a);
    d[o] = fmaxf(a, 0.f);
  }
  float* op = out + (size_t)n*NODE_F;
  #pragma unroll 8
  for (int o = 0; o < NODE_F; o++) {
    float a = d2bs[o];
    #pragma unroll
    for (int j = 0; j < HID; j++) a = fmaf(d[j], d2s[j*NODE_F+o], a);
    op[o] = a;
  }
}

// ---------------- cooperative fused kernel ----------------

struct FusedArgs {
  const float *x, *ea;
  const int *ei;
  const float *liw, *lib, *eb1, *rw, *rb, *low, *lob, *d1w, *d1b, *d2w, *d2b;
  const float *ew1, *ew2, *eb2;
  float *out, *h0, *h1, *agg;
  int *deg, *off, *cursor, *csrs, *csre, *csrd, *bsum;
  unsigned short *w2a, *w1p;
};

__global__ __launch_bounds__(256, 2) void k_fused(FusedArgs a) {
  __shared__ float smem[256*33 + 512];   // 35.8 KB; aliased per phase
  cg::grid_group grid = cg::this_grid();
  const int tid = threadIdx.x;
  const int bid = blockIdx.x;
  const int gidx = bid*256 + tid;        // 0..131071

  // ---- P0: prep (w2a/w1p/deg) + agg zero + lin_in ----
  {
    float* Ws = smem;                    // 2048 f
    float* bs = smem + NODE_F*HID;       // 32 f
    for (int i = tid; i < NODE_F*HID; i += 256) Ws[i] = a.liw[i];
    if (tid < HID) bs[tid] = a.lib[tid];
    __syncthreads();
    dev_prep_item(gidx, a.ew2, a.eb2, a.ew1, a.w2a, a.w1p, a.deg);
    float4 z4 = make_float4(0.f,0.f,0.f,0.f);
    float4* a4 = (float4*)a.agg;
    for (int i = gidx; i < N_NODES*HID/4; i += FUSED_THREADS) a4[i] = z4;
    for (int t = gidx; t < N_NODES*HID; t += FUSED_THREADS)
      dev_lin_item(t, a.x, Ws, bs, a.h0);
  }
  grid.sync();

  // ---- P1: hist ----
  for (int t = gidx; t < N_EDGES; t += FUSED_THREADS) dev_hist_item(t, a.ei, a.deg);
  grid.sync();

  // ---- P2: scan1 ----
  if (bid < SCAN_BLOCKS) dev_scan1(bid, tid, (int*)smem, a.deg, a.off, a.bsum);
  grid.sync();

  // ---- P3: scan23 ----
  if (bid < SCAN_BLOCKS) dev_scan23(bid, tid, (int*)smem, a.off, a.bsum, a.cursor);
  grid.sync();

  // ---- P4: scatter ----
  for (int t = gidx; t < N_EDGES; t += FUSED_THREADS)
    dev_scatter_item(t, a.ei, a.off, a.cursor, a.csrs, a.csre, a.csrd);
  grid.sync();

  // ---- layers ----
  float* sHE = smem;
  int* sSRC = (int*)(smem + 256*33);
  int* sEID = sSRC + 256;
  const float* hin = a.h0;
  float* hout = a.h1;
  #pragma unroll 1
  for (int l = 0; l < 3; l++) {
    const unsigned short* w1pl = a.w1p + (size_t)l*1024;
    const float* b1 = a.eb1 + l*HID;
    const unsigned short* w2al = a.w2a + (size_t)l*W2A_L;
    #pragma unroll 1
    for (int t5 = bid; t5 < NTILES; t5 += gridDim.x) {
      __syncthreads();   // protect smem reuse across tiles / phases
      dev_msgagg_tile(sHE, sSRC, sEID, t5, tid, hin, a.ea, w1pl, b1, w2al,
                      a.csrs, a.csre, a.csrd, a.off, a.agg);
    }
    grid.sync();
    if (l < 2) {
      float* rws = smem;            // 1024 f
      float* rbs = smem + HID*HID;  // 32 f
      for (int i = tid; i < HID*HID; i += 256) rws[i] = a.rw[(size_t)l*HID*HID + i];
      if (tid < HID) rbs[tid] = a.rb[l*HID + tid];
      __syncthreads();
      for (int t = gidx; t < N_NODES*8; t += FUSED_THREADS)
        dev_root_item(t, a.agg, a.off, hin, rws, rbs, hout);
      grid.sync();
      const float* tmp = hin; hin = hout; hout = (float*)tmp;
    }
  }

  // ---- decoder (layer-3 root fused) ----
  {
    float* rws  = smem;        // 1024
    float* rbs  = smem + 1024; // 32
    float* lows = smem + 1056; // 512
    float* lobs = smem + 1568; // 16
    float* d1s  = smem + 1584; // 512
    float* d1bs = smem + 2096; // 32
    float* d2s  = smem + 2128; // 2048
    float* d2bs = smem + 4176; // 64
    for (int i = tid; i < HID*HID; i += 256) rws[i] = a.rw[(size_t)2*HID*HID + i];
    for (int i = tid; i < HID; i += 256) rbs[i] = a.rb[2*HID + i];
    for (int i = tid; i < HID*LAT; i += 256) lows[i] = a.low[i];
    for (int i = tid; i < LAT; i += 256) lobs[i] = a.lob[i];
    for (int i = tid; i < LAT*HID; i += 256) d1s[i] = a.d1w[i];
    for (int i = tid; i < HID; i += 256) d1bs[i] = a.d1b[i];
    for (int i = tid; i < HID*NODE_F; i += 256) d2s[i] = a.d2w[i];
    for (int i = tid; i < NODE_F; i += 256) d2bs[i] = a.d2b[i];
    __syncthreads();
    if (gidx < N_NODES)
      dev_decoder_node(gidx, a.agg, a.off, hin, rws, rbs, lows, lobs,
                       d1s, d1bs, d2s, d2bs, a.out);
  }
}

// ---------------- fallback multi-launch kernels (R2 path) ----------------

__global__ void k_prep(const float* __restrict__ ew2, const float* __restrict__ eb2,
                       const float* __restrict__ ew1,
                       unsigned short* __restrict__ w2a,
                       unsigned short* __restrict__ w1p,
                       int* __restrict__ deg,
                       float* __restrict__ agg) {
  int g = blockIdx.x*256 + threadIdx.x;          // 396*256 = 101376
  dev_prep_item(g, ew2, eb2, ew1, w2a, w1p, deg);
  float4 z4 = make_float4(0.f,0.f,0.f,0.f);
  float4* a4 = (float4*)agg;
  for (int i = g; i < N_NODES*HID/4; i += 101376) a4[i] = z4;
}

__global__ void k_hist(const int* __restrict__ ei, int* __restrict__ deg) {
  int t = blockIdx.x*256 + threadIdx.x;
  if (t >= N_EDGES) return;
  dev_hist_item(t, ei, deg);
}

__global__ __launch_bounds__(256) void k_scan1(const int* __restrict__ deg,
                                               int* __restrict__ off,
                                               int* __restrict__ bsum) {
  __shared__ int s[256];
  dev_scan1(blockIdx.x, threadIdx.x, s, deg, off, bsum);
}

__global__ __launch_bounds__(256) void k_scan23(int* __restrict__ off,
                                                const int* __restrict__ bsum,
                                                int* __restrict__ cursor) {
  __shared__ int sPref[1];
  dev_scan23(blockIdx.x, threadIdx.x, sPref, off, bsum, cursor);
}

__global__ void k_scatter(const int* __restrict__ ei, const int* __restrict__ off,
                          int* __restrict__ cursor,
                          int* __restrict__ csr_src, int* __restrict__ csr_eid,
                          int* __restrict__ csr_dst) {
  int t = blockIdx.x*256 + threadIdx.x;
  if (t >= N_EDGES) return;
  dev_scatter_item(t, ei, off, cursor, csr_src, csr_eid, csr_dst);
}

__global__ void k_lin_in(const float* __restrict__ x,
                         const float* __restrict__ W,
                         const float* __restrict__ b,
                         float* __restrict__ h) {
  __shared__ float Ws[NODE_F*HID];
  __shared__ float bs[HID];
  for (int i = threadIdx.x; i < NODE_F*HID; i += 256) Ws[i] = W[i];
  if (threadIdx.x < HID) bs[threadIdx.x] = b[threadIdx.x];
  __syncthreads();
  int t = blockIdx.x*256 + threadIdx.x;
  if (t >= N_NODES*HID) return;
  dev_lin_item(t, x, Ws, bs, h);
}

__global__ __launch_bounds__(256) void k_msgagg(const float* __restrict__ hin,
                                                const float* __restrict__ ea,
                                                const unsigned short* __restrict__ w1pl,
                                                const float* __restrict__ b1,
                                                const unsigned short* __restrict__ w2al,
                                                const int* __restrict__ csr_src,
                                                const int* __restrict__ csr_eid,
                                                const int* __restrict__ csr_dst,
                                                const int* __restrict__ off,
                                                float* __restrict__ agg) {
  __shared__ float sHE[256*33];
  __shared__ int   sSRC[256];
  __shared__ int   sEID[256];
  dev_msgagg_tile(sHE, sSRC, sEID, blockIdx.x, threadIdx.x, hin, ea, w1pl, b1,
                  w2al, csr_src, csr_eid, csr_dst, off, agg);
}

__global__ void k_root(float* __restrict__ agg,
                       const int* __restrict__ off,
                       const float* __restrict__ hin,
                       const float* __restrict__ rw,
                       const float* __restrict__ rb,
                       float* __restrict__ hout) {
  __shared__ float rws[HID*HID];
  __shared__ float rbs[HID];
  for (int i = threadIdx.x; i < HID*HID; i += 256) rws[i] = rw[i];
  if (threadIdx.x < HID) rbs[threadIdx.x] = rb[threadIdx.x];
  __syncthreads();
  int t = blockIdx.x*256 + threadIdx.x;
  if (t >= N_NODES*8) return;
  dev_root_item(t, agg, off, hin, rws, rbs, hout);
}

__global__ void k_decoder(const float* __restrict__ agg,
                          const int* __restrict__ off,
                          const float* __restrict__ h,
                          const float* __restrict__ rw, const float* __restrict__ rb,
                          const float* __restrict__ lo_w, const float* __restrict__ lo_b,
                          const float* __restrict__ d1_w, const float* __restrict__ d1_b,
                          const float* __restrict__ d2_w, const float* __restrict__ d2_b,
                          float* __restrict__ out) {
  __shared__ float rws[HID*HID], rbs[HID];
  __shared__ float lows[HID*LAT], lobs[LAT], d1s[LAT*HID], d1bs[HID], d2s[HID*NODE_F], d2bs[NODE_F];
  for (int i = threadIdx.x; i < HID*HID; i += 256) rws[i] = rw[i];
  for (int i = threadIdx.x; i < HID; i += 256) rbs[i] = rb[i];
  for (int i = threadIdx.x; i < HID*LAT; i += 256) lows[i] = lo_w[i];
  for (int i = threadIdx.x; i < LAT; i += 256) lobs[i] = lo_b[i];
  for (int i = threadIdx.x; i < LAT*HID; i += 256) d1s[i] = d1_w[i];
  for (int i = threadIdx.x; i < HID; i += 256) d1bs[i] = d1_b[i];
  for (int i = threadIdx.x; i < HID*NODE_F; i += 256) d2s[i] = d2_w[i];
  for (int i = threadIdx.x; i < NODE_F; i += 256) d2bs[i] = d2_b[i];
  __syncthreads();
  int n = blockIdx.x*256 + threadIdx.x;
  if (n >= N_NODES) return;
  dev_decoder_node(n, agg, off, h, rws, rbs, lows, lobs, d1s, d1bs, d2s, d2bs, out);
}

extern "C" void kernel_launch(void* const* d_in, const int* in_sizes, int n_in,
                              void* d_out, int out_size, void* d_ws, size_t ws_size,
                              hipStream_t stream) {
  const float* x   = (const float*)d_in[0];
  const int*   ei  = (const int*)d_in[1];
  const float* ea  = (const float*)d_in[2];
  const float* liw = (const float*)d_in[3];
  const float* lib = (const float*)d_in[4];
  const float* ew1 = (const float*)d_in[5];
  const float* eb1 = (const float*)d_in[6];
  const float* ew2 = (const float*)d_in[7];
  const float* eb2 = (const float*)d_in[8];
  const float* rw  = (const float*)d_in[9];
  const float* rb  = (const float*)d_in[10];
  const float* low = (const float*)d_in[11];
  const float* lob = (const float*)d_in[12];
  const float* d1w = (const float*)d_in[13];
  const float* d1b = (const float*)d_in[14];
  const float* d2w = (const float*)d_in[15];
  const float* d2b = (const float*)d_in[16];
  float* out = (float*)d_out;

  float* h0   = (float*)d_ws;                          // 1.6M f
  float* h1   = h0  + (size_t)N_NODES*HID;             // 1.6M f
  float* agg  = h1  + (size_t)N_NODES*HID;             // 1.6M f (f32 aggregation)
  int*  deg   = (int*)(agg + (size_t)N_NODES*HID);     // 50k
  int*  off   = deg + N_NODES;                         // 50k+1 (alloc 50016)
  int*  cursor= off + N_NODES + 16;                    // 50k
  int*  csrs  = cursor + N_NODES;                      // 200k  csr_src
  int*  csre  = csrs + N_EDGES;                        // 200k  csr_eid
  int*  csrd  = csre + N_EDGES;                        // 200k  csr_dst
  int*  bsum  = csrd + N_EDGES;                        // 256
  unsigned short* w2a = (unsigned short*)(bsum + 256); // 3*33792 bf16
  unsigned short* w1p = w2a + 3*W2A_L;                 // 3*1024 bf16

  FusedArgs fa;
  fa.x = x; fa.ea = ea; fa.ei = ei;
  fa.liw = liw; fa.lib = lib; fa.eb1 = eb1; fa.rw = rw; fa.rb = rb;
  fa.low = low; fa.lob = lob; fa.d1w = d1w; fa.d1b = d1b; fa.d2w = d2w; fa.d2b = d2b;
  fa.ew1 = ew1; fa.ew2 = ew2; fa.eb2 = eb2;
  fa.out = out; fa.h0 = h0; fa.h1 = h1; fa.agg = agg;
  fa.deg = deg; fa.off = off; fa.cursor = cursor;
  fa.csrs = csrs; fa.csre = csre; fa.csrd = csrd; fa.bsum = bsum;
  fa.w2a = w2a; fa.w1p = w1p;

  void* kp[] = { (void*)&fa };
  hipError_t err = hipLaunchCooperativeKernel((const void*)k_fused,
      dim3(FUSED_BLOCKS), dim3(256), kp, 0, stream);
  if (err == hipSuccess) return;
  (void)hipGetLastError();   // clear error state, fall back to multi-launch path

  k_prep<<<(3*W2A_L)/256, 256, 0, stream>>>(ew2, eb2, ew1, w2a, w1p, deg, agg);
  k_hist<<<(N_EDGES + 255)/256, 256, 0, stream>>>(ei, deg);
  k_scan1<<<SCAN_BLOCKS, 256, 0, stream>>>(deg, off, bsum);
  k_scan23<<<SCAN_BLOCKS, 256, 0, stream>>>(off, bsum, cursor);
  k_scatter<<<(N_EDGES + 255)/256, 256, 0, stream>>>(ei, off, cursor, csrs, csre, csrd);

  k_lin_in<<<(N_NODES*HID + 255)/256, 256, 0, stream>>>(x, liw, lib, h0);

  // L1
  k_msgagg<<<NTILES, 256, 0, stream>>>(h0, ea, w1p, eb1,
      w2a, csrs, csre, csrd, off, agg);
  k_root<<<(N_NODES*8 + 255)/256, 256, 0, stream>>>(agg, off, h0, rw, rb, h1);
  // L2
  k_msgagg<<<NTILES, 256, 0, stream>>>(h1, ea, w1p + 1024, eb1 + HID,
      w2a + (size_t)W2A_L, csrs, csre, csrd, off, agg);
  k_root<<<(N_NODES*8 + 255)/256, 256, 0, stream>>>(agg, off, h1, rw + HID*HID, rb + HID, h0);
  // L3 (root fused into decoder)
  k_msgagg<<<NTILES, 256, 0, stream>>>(h0, ea, w1p + 2048, eb1 + 2*HID,
      w2a + (size_t)2*W2A_L, csrs, csre, csrd, off, agg);
  k_decoder<<<(N_NODES + 255)/256, 256, 0, stream>>>(agg, off, h0,
      rw + 2*HID*HID, rb + 2*HID, low, lob, d1w, d1b, d2w, d2b, out);
}

// Round 4
// 353.212 us; speedup vs baseline: 2.4282x; 2.4282x over previous
//
#include <hip/hip_runtime.h>
#include <hip/hip_bf16.h>
#include <stdint.h>

#define N_NODES 50000
#define N_EDGES 200000
#define NODE_F 64
#define EDGE_F 16
#define HID 32
#define LAT 16
#define W2A_L 33792 // per-layer w2a elements: 33 k-steps * 2 m-tiles * 64 lanes * 8
#define NTILES 782  // (N_EDGES+255)/256
#define MEGA_BLOCKS 1024
#define MEGA_THREADS (MEGA_BLOCKS*256)
#define CHUNK 49    // 1024*49 = 50176 >= 50000

typedef __attribute__((ext_vector_type(8))) short short8;   // 8 bf16 = 4 VGPR
typedef __attribute__((ext_vector_type(4))) float f32x4;
typedef __attribute__((ext_vector_type(2))) float f32x2;

static __device__ __forceinline__ unsigned short bfbits(float f) {
  union { __hip_bfloat16 h; unsigned short s; } c; c.h = __float2bfloat16(f); return c.s;
}
// Truncation pack: 1x v_perm_b32. lo16 = top of bits(v.x), hi16 = top of bits(v.y).
static __device__ __forceinline__ unsigned pkt(f32x2 v) {
  return __builtin_amdgcn_perm(__float_as_uint(v.y), __float_as_uint(v.x), 0x07060302u);
}
union AFrag { short8 v; unsigned u[4]; };

// ---- mega prelude: w2a/w1p transpose + hist atomics + lin_in + agg zero ----
// All mutually independent (deg pre-zeroed by hipMemsetAsync before this kernel).
// w2a[l][k][mt][lane][j] = A-frag element A[m = mt*16 + (lane&15)][kk = (lane>>4)*8 + j]
//   where A[m][h] = w2[k][h*32 + m]  (k<32), or b2[h*32 + m] (k==32 bias fold).
__global__ __launch_bounds__(256) void k_mega(
    const float* __restrict__ ew2, const float* __restrict__ eb2,
    const float* __restrict__ ew1,
    const int* __restrict__ ei,
    const float* __restrict__ x, const float* __restrict__ liw,
    const float* __restrict__ lib,
    unsigned short* __restrict__ w2a, unsigned short* __restrict__ w1p,
    int* __restrict__ deg, float* __restrict__ agg, float* __restrict__ h0) {
  __shared__ float Ws[NODE_F*HID];
  __shared__ float bs[HID];
  for (int i = threadIdx.x; i < NODE_F*HID; i += 256) Ws[i] = liw[i];
  if (threadIdx.x < HID) bs[threadIdx.x] = lib[threadIdx.x];
  __syncthreads();
  const int g = blockIdx.x*256 + threadIdx.x;     // 0..262143

  // w2a transpose (bf16 A-frags, bias folded as k=32)
  if (g < 3*W2A_L) {
    int l = g / W2A_L;
    int r = g % W2A_L;
    int k = r >> 10;            // 0..32
    int r2 = r & 1023;
    int mt = r2 >> 9;           // 0..1
    int ln = (r2 >> 3) & 63;
    int j  = r2 & 7;
    int h  = (ln >> 4)*8 + j;   // 0..31
    int m  = mt*16 + (ln & 15); // 0..31
    float v = (k < 32) ? ew2[(size_t)l*32768 + k*1024 + h*32 + m]
                       : eb2[(size_t)l*1024 + h*32 + m];
    w2a[g] = bfbits(v);
  }
  // w1p[l][nt][lane][j] = B-frag element B[k=(lane>>4)*8+j][n=nt*16+(lane&15)]
  if (g < 3*2*64*8) {
    int l2 = g >> 10;
    int r3 = g & 1023;
    int nt = r3 >> 9;
    int ln2 = (r3 >> 3) & 63;
    int j2  = r3 & 7;
    int kgr = ln2 >> 4;
    float w = (kgr < 2) ? ew1[(size_t)l2*512 + (kgr*8 + j2)*32 + nt*16 + (ln2 & 15)] : 0.f;
    w1p[g] = bfbits(w);
  }
  // degree histogram (deg pre-zeroed)
  if (g < N_EDGES) {
    int d = ei[N_EDGES + g];
    d = min(max(d, 0), N_NODES-1);
    atomicAdd(&deg[d], 1);
  }
  // agg zero (layer-1 boundary atomics + zero-degree nodes)
  {
    float4 z4 = make_float4(0.f,0.f,0.f,0.f);
    float4* a4 = (float4*)agg;
    for (int i = g; i < N_NODES*HID/4; i += MEGA_THREADS) a4[i] = z4;
  }
  // lin_in: h0 = relu(x @ W + b)
  for (int t = g; t < N_NODES*HID; t += MEGA_THREADS) {
    int n = t >> 5, o = t & 31;
    const float4* xp = (const float4*)(x + (size_t)n*NODE_F);
    float acc = bs[o];
    #pragma unroll
    for (int j = 0; j < NODE_F/4; j++) {
      float4 v = xp[j];
      acc = fmaf(v.x, Ws[(4*j+0)*HID+o], acc);
      acc = fmaf(v.y, Ws[(4*j+1)*HID+o], acc);
      acc = fmaf(v.z, Ws[(4*j+2)*HID+o], acc);
      acc = fmaf(v.w, Ws[(4*j+3)*HID+o], acc);
    }
    h0[t] = fmaxf(acc, 0.f);
  }
}

// single-block exclusive scan of deg -> off, plus cursor zero and off[N]=E.
__global__ __launch_bounds__(1024) void k_scan_one(const int* __restrict__ deg,
                                                   int* __restrict__ off,
                                                   int* __restrict__ cursor) {
  __shared__ int s[1024];
  const int tid = threadIdx.x;
  const int lo = tid*CHUNK;
  int loc[CHUNK];
  int sum = 0;
  #pragma unroll
  for (int c = 0; c < CHUNK; c++) {
    int i = lo + c;
    int d = (i < N_NODES) ? deg[i] : 0;
    loc[c] = sum;          // exclusive running within chunk
    sum += d;
  }
  s[tid] = sum; __syncthreads();
  int v = sum;
  #pragma unroll
  for (int ofs = 1; ofs < 1024; ofs <<= 1) {
    int w = (tid >= ofs) ? s[tid-ofs] : 0;
    __syncthreads();
    v += w; s[tid] = v;
    __syncthreads();
  }
  const int base = v - sum;  // exclusive prefix of this thread's chunk
  #pragma unroll
  for (int c = 0; c < CHUNK; c++) {
    int i = lo + c;
    if (i < N_NODES) { off[i] = base + loc[c]; cursor[i] = 0; }
  }
  if (tid == 1023) off[N_NODES] = N_EDGES;
}

// emits CSR-ordered edge metadata: src node, original edge id, dst node
__global__ void k_scatter(const int* __restrict__ ei, const int* __restrict__ off,
                          int* __restrict__ cursor,
                          int* __restrict__ csr_src, int* __restrict__ csr_eid,
                          int* __restrict__ csr_dst) {
  int t = blockIdx.x*256 + threadIdx.x;
  if (t >= N_EDGES) return;
  int d = ei[N_EDGES + t];
  d = min(max(d, 0), N_NODES-1);
  int s = ei[t];
  s = min(max(s, 0), N_NODES-1);
  int pos = off[d] + atomicAdd(&cursor[d], 1);
  csr_src[pos] = s;
  csr_eid[pos] = t;
  csr_dst[pos] = d;
}

// Fused msg + CSR aggregation (identical to R2). Edges in CSR order; each
// block's 256 edges cover a contiguous destination-node run. Messages land in
// the LDS tile (f32), then block-level run-sum: interior nodes -> direct
// float4 store into agg; boundary nodes -> f32 atomics. agg pre-zeroed.
__global__ __launch_bounds__(256) void k_msgagg(const float* __restrict__ hin,
                                                const float* __restrict__ ea,
                                                const unsigned short* __restrict__ w1pl,
                                                const float* __restrict__ b1,
                                                const unsigned short* __restrict__ w2al,
                                                const int* __restrict__ csr_src,
                                                const int* __restrict__ csr_eid,
                                                const int* __restrict__ csr_dst,
                                                const int* __restrict__ off,
                                                float* __restrict__ agg) {
  __shared__ float sHE[256*33];   // he[e][0..32] then (aliased) msg[e][0..31]; stride 33
  __shared__ int   sSRC[256];
  __shared__ int   sEID[256];
  const int tid = threadIdx.x;
  const int be  = blockIdx.x*256;
  const int wv   = tid >> 6;          // wave 0..3
  const int lane = tid & 63;
  const int nn   = lane & 15;
  const int quad = lane >> 4;
  const int wbase = wv*64;            // this wave's 64 edges (local CSR positions)

  // per-wave staging of src/eid + bias K-row (all lanes)
  {
    int el = wbase + lane;
    int pos = min(be + el, N_EDGES-1);
    sSRC[el] = csr_src[pos];
    sEID[el] = csr_eid[pos];
    sHE[el*33 + 32] = 1.0f;
  }

  // --- he via MFMA: 4 M-tiles x 2 N-halves (wave-internal) ---
  {
    short8 wb0 = *(const short8*)(w1pl + lane*8);         // nt=0
    short8 wb1 = *(const short8*)(w1pl + 512 + lane*8);   // nt=1
    f32x4 z = {0.f,0.f,0.f,0.f};
    float bv0 = b1[nn], bv1 = b1[nn + 16];
    #pragma unroll
    for (int t = 0; t < 4; t++) {
      AFrag a;
      if (quad < 2) {
        int e = sEID[wbase + t*16 + nn];
        const float4* p = (const float4*)(ea + (size_t)e*EDGE_F + quad*8);
        float4 u = p[0], v = p[1];
        a.u[0] = pkt(f32x2{u.x,u.y}); a.u[1] = pkt(f32x2{u.z,u.w});
        a.u[2] = pkt(f32x2{v.x,v.y}); a.u[3] = pkt(f32x2{v.z,v.w});
      } else {
        #pragma unroll
        for (int i = 0; i < 4; i++) a.u[i] = 0u;
      }
      f32x4 h0 = __builtin_amdgcn_mfma_f32_16x16x32_bf16(a.v, wb0, z, 0, 0, 0);
      f32x4 h1 = __builtin_amdgcn_mfma_f32_16x16x32_bf16(a.v, wb1, z, 0, 0, 0);
      #pragma unroll
      for (int r = 0; r < 4; r++) {
        int ro = (wbase + t*16 + quad*4 + r)*33;
        sHE[ro + nn]      = fmaxf(h0[r] + bv0, 0.f);
        sHE[ro + 16 + nn] = fmaxf(h1[r] + bv1, 0.f);
      }
    }
  }
  // no barrier: all sHE producer/consumer pairs so far are wave-internal

  // B-frags: x^T per tile, packed ONCE (lane: edge=nn, k=h=quad*8+j)
  short8 bx[4];
  #pragma unroll
  for (int t = 0; t < 4; t++) {
    int si = sSRC[wbase + t*16 + nn];
    const float4* p = (const float4*)(hin + (size_t)si*HID + quad*8);
    float4 a = p[0], b = p[1];
    AFrag f;
    f.u[0] = pkt(f32x2{a.x,a.y}); f.u[1] = pkt(f32x2{a.z,a.w});
    f.u[2] = pkt(f32x2{b.x,b.y}); f.u[3] = pkt(f32x2{b.z,b.w});
    bx[t] = f.v;
  }

  f32x4 c0[4], c1[4];
  #pragma unroll
  for (int t = 0; t < 4; t++) { c0[t] = f32x4{0.f,0.f,0.f,0.f}; c1[t] = c0[t]; }
  const f32x4 zz = {0.f,0.f,0.f,0.f};

  const unsigned short* ap = w2al + (unsigned)lane*8;   // [k][mt][lane][8]
  const float* heR[4];
  #pragma unroll
  for (int t = 0; t < 4; t++) heR[t] = sHE + (wbase + t*16 + nn)*33;

  // depth-3 pipeline slots: A-frags (W_k^T, both M-tiles) + he scalars
  short8 sa0[3], sa1[3];
  float  sh[3][4];
  #pragma unroll
  for (int j = 0; j < 3; j++) {
    sa0[j] = *(const short8*)(ap + j*1024);
    sa1[j] = *(const short8*)(ap + j*1024 + 512);
    #pragma unroll
    for (int t = 0; t < 4; t++) sh[j][t] = heR[t][j];
  }

  #pragma unroll 1
  for (int base = 0; base < 30; base += 3) {
    #pragma unroll
    for (int j = 0; j < 3; j++) {
      const int kk = base + j;
      short8 a0 = sa0[j], a1 = sa1[j];
      #pragma unroll
      for (int t = 0; t < 4; t++) {
        f32x4 u0 = __builtin_amdgcn_mfma_f32_16x16x32_bf16(a0, bx[t], zz, 0, 0, 0);
        f32x4 u1 = __builtin_amdgcn_mfma_f32_16x16x32_bf16(a1, bx[t], zz, 0, 0, 0);
        float hk = sh[j][t];
        #pragma unroll
        for (int r = 0; r < 4; r++) {
          c0[t][r] = fmaf(hk, u0[r], c0[t][r]);
          c1[t][r] = fmaf(hk, u1[r], c1[t][r]);
        }
      }
      sa0[j] = *(const short8*)(ap + (kk+3)*1024);
      sa1[j] = *(const short8*)(ap + (kk+3)*1024 + 512);
      #pragma unroll
      for (int t = 0; t < 4; t++) sh[j][t] = heR[t][kk+3];
    }
  }
  #pragma unroll
  for (int j = 0; j < 3; j++) {
    short8 a0 = sa0[j], a1 = sa1[j];
    #pragma unroll
    for (int t = 0; t < 4; t++) {
      f32x4 u0 = __builtin_amdgcn_mfma_f32_16x16x32_bf16(a0, bx[t], zz, 0, 0, 0);
      f32x4 u1 = __builtin_amdgcn_mfma_f32_16x16x32_bf16(a1, bx[t], zz, 0, 0, 0);
      float hk = sh[j][t];
      #pragma unroll
      for (int r = 0; r < 4; r++) {
        c0[t][r] = fmaf(hk, u0[r], c0[t][r]);
        c1[t][r] = fmaf(hk, u1[r], c1[t][r]);
      }
    }
  }

  // msg -> LDS, aliasing this wave's own sHE rows (wave-internal WAR)
  #pragma unroll
  for (int t = 0; t < 4; t++) {
    int ro = (wbase + t*16 + nn)*33 + quad*4;
    sHE[ro + 0]  = c0[t][0]; sHE[ro + 1]  = c0[t][1];
    sHE[ro + 2]  = c0[t][2]; sHE[ro + 3]  = c0[t][3];
    sHE[ro + 16] = c1[t][0]; sHE[ro + 17] = c1[t][1];
    sHE[ro + 18] = c1[t][2]; sHE[ro + 19] = c1[t][3];
  }
  __syncthreads();

  // block-level CSR-run aggregation from the LDS msg tile
  const int s    = be;
  const int wend = s + 256;
  const int nF = csr_dst[min(s,       N_EDGES-1)];
  const int nL = csr_dst[min(s + 255, N_EDGES-1)];
  for (int basei = 0; basei <= nL - nF; basei += 32) {
    int idx = basei + (tid >> 3);
    int n = nF + idx;
    if (n <= nL) {
      int oc = tid & 7;
      int s0 = off[n], s1 = off[n+1];
      int lo = max(s0, s) - s;
      int hi = min(s1, wend) - s;
      float a0 = 0.f, a1 = 0.f, a2 = 0.f, a3 = 0.f;
      for (int j = lo; j < hi; j++) {
        const float* row = sHE + j*33 + oc*4;
        a0 += row[0]; a1 += row[1]; a2 += row[2]; a3 += row[3];
      }
      float* dst = agg + (size_t)n*HID + oc*4;
      if (s0 >= s && s1 <= wend) {
        *(float4*)dst = make_float4(a0, a1, a2, a3);
      } else {
        atomicAdd(dst + 0, a0); atomicAdd(dst + 1, a1);
        atomicAdd(dst + 2, a2); atomicAdd(dst + 3, a3);
      }
    }
  }
}

// hout = relu( agg/deg + hin @ root_w + root_b ); re-zeroes agg for next layer.
__global__ void k_root(float* __restrict__ agg,
                       const int* __restrict__ off,
                       const float* __restrict__ hin,
                       const float* __restrict__ rw,
                       const float* __restrict__ rb,
                       float* __restrict__ hout) {
  __shared__ float rws[HID*HID];
  __shared__ float rbs[HID];
  for (int i = threadIdx.x; i < HID*HID; i += 256) rws[i] = rw[i];
  if (threadIdx.x < HID) rbs[threadIdx.x] = rb[threadIdx.x];
  __syncthreads();
  int t = blockIdx.x*256 + threadIdx.x;
  if (t >= N_NODES*8) return;
  int n = t >> 3, oc = t & 7;
  float4* ap = (float4*)(agg + (size_t)n*HID);
  float4 av = ap[oc];
  float inv = 1.f / fmaxf((float)(off[n+1] - off[n]), 1.f);
  float a0 = fmaf(av.x, inv, rbs[oc*4+0]);
  float a1 = fmaf(av.y, inv, rbs[oc*4+1]);
  float a2 = fmaf(av.z, inv, rbs[oc*4+2]);
  float a3 = fmaf(av.w, inv, rbs[oc*4+3]);
  const float4* hp = (const float4*)(hin + (size_t)n*HID);
  #pragma unroll
  for (int jq = 0; jq < 8; jq++) {
    float4 hv = hp[jq];
    #pragma unroll
    for (int c = 0; c < 4; c++) {
      int j = jq*4 + c;
      float h = (c==0)?hv.x:(c==1)?hv.y:(c==2)?hv.z:hv.w;
      const float4* rp = (const float4*)(rws + j*HID + oc*4);
      float4 r = rp[0];
      a0 = fmaf(h, r.x, a0);
      a1 = fmaf(h, r.y, a1);
      a2 = fmaf(h, r.z, a2);
      a3 = fmaf(h, r.w, a3);
    }
  }
  ((float4*)(hout + (size_t)n*HID))[oc] =
      make_float4(fmaxf(a0,0.f), fmaxf(a1,0.f), fmaxf(a2,0.f), fmaxf(a3,0.f));
  ap[oc] = make_float4(0.f, 0.f, 0.f, 0.f);   // ready for next layer
}

// layer-3 root fused in: hr = relu(agg/deg + h@rw + rb), then
// out = (relu((hr@lo_w+lo_b)@d1_w+d1_b))@d2_w+d2_b   (no relu on z)
__global__ void k_decoder(const float* __restrict__ agg,
                          const int* __restrict__ off,
                          const float* __restrict__ h,
                          const float* __restrict__ rw, const float* __restrict__ rb,
                          const float* __restrict__ lo_w, const float* __restrict__ lo_b,
                          const float* __restrict__ d1_w, const float* __restrict__ d1_b,
                          const float* __restrict__ d2_w, const float* __restrict__ d2_b,
                          float* __restrict__ out) {
  __shared__ float rws[HID*HID], rbs[HID];
  __shared__ float lows[HID*LAT], lobs[LAT], d1s[LAT*HID], d1bs[HID], d2s[HID*NODE_F], d2bs[NODE_F];
  for (int i = threadIdx.x; i < HID*HID; i += 256) rws[i] = rw[i];
  for (int i = threadIdx.x; i < HID; i += 256) rbs[i] = rb[i];
  for (int i = threadIdx.x; i < HID*LAT; i += 256) lows[i] = lo_w[i];
  for (int i = threadIdx.x; i < LAT; i += 256) lobs[i] = lo_b[i];
  for (int i = threadIdx.x; i < LAT*HID; i += 256) d1s[i] = d1_w[i];
  for (int i = threadIdx.x; i < HID; i += 256) d1bs[i] = d1_b[i];
  for (int i = threadIdx.x; i < HID*NODE_F; i += 256) d2s[i] = d2_w[i];
  for (int i = threadIdx.x; i < NODE_F; i += 256) d2bs[i] = d2_b[i];
  __syncthreads();
  int n = blockIdx.x*256 + threadIdx.x;
  if (n >= N_NODES) return;
  float hv[HID], av[HID];
  const float4* hp = (const float4*)(h + (size_t)n*HID);
  const float4* ap = (const float4*)(agg + (size_t)n*HID);
  #pragma unroll
  for (int i = 0; i < HID/4; i++) {
    float4 v = hp[i]; hv[4*i]=v.x; hv[4*i+1]=v.y; hv[4*i+2]=v.z; hv[4*i+3]=v.w;
    float4 a = ap[i]; av[4*i]=a.x; av[4*i+1]=a.y; av[4*i+2]=a.z; av[4*i+3]=a.w;
  }
  float inv = 1.f / fmaxf((float)(off[n+1] - off[n]), 1.f);
  float hr[HID];
  #pragma unroll 4
  for (int o = 0; o < HID; o++) {
    float a = fmaf(av[o], inv, rbs[o]);
    #pragma unroll
    for (int j = 0; j < HID; j++) a = fmaf(hv[j], rws[j*HID+o], a);
    hr[o] = fmaxf(a, 0.f);
  }
  float z[LAT];
  #pragma unroll
  for (int o = 0; o < LAT; o++) {
    float a = lobs[o];
    #pragma unroll
    for (int j = 0; j < HID; j++) a = fmaf(hr[j], lows[j*LAT+o], a);
    z[o] = a;
  }
  float d[HID];
  #pragma unroll
  for (int o = 0; o < HID; o++) {
    float a = d1bs[o];
    #pragma unroll
    for (int j = 0; j < LAT; j++) a = fmaf(z[j], d1s[j*HID+o], a);
    d[o] = fmaxf(a, 0.f);
  }
  float* op = out + (size_t)n*NODE_F;
  #pragma unroll 8
  for (int o = 0; o < NODE_F; o++) {
    float a = d2bs[o];
    #pragma unroll
    for (int j = 0; j < HID; j++) a = fmaf(d[j], d2s[j*NODE_F+o], a);
    op[o] = a;
  }
}

extern "C" void kernel_launch(void* const* d_in, const int* in_sizes, int n_in,
                              void* d_out, int out_size, void* d_ws, size_t ws_size,
                              hipStream_t stream) {
  const float* x   = (const float*)d_in[0];
  const int*   ei  = (const int*)d_in[1];
  const float* ea  = (const float*)d_in[2];
  const float* liw = (const float*)d_in[3];
  const float* lib = (const float*)d_in[4];
  const float* ew1 = (const float*)d_in[5];
  const float* eb1 = (const float*)d_in[6];
  const float* ew2 = (const float*)d_in[7];
  const float* eb2 = (const float*)d_in[8];
  const float* rw  = (const float*)d_in[9];
  const float* rb  = (const float*)d_in[10];
  const float* low = (const float*)d_in[11];
  const float* lob = (const float*)d_in[12];
  const float* d1w = (const float*)d_in[13];
  const float* d1b = (const float*)d_in[14];
  const float* d2w = (const float*)d_in[15];
  const float* d2b = (const float*)d_in[16];
  float* out = (float*)d_out;

  float* h0   = (float*)d_ws;                          // 1.6M f
  float* h1   = h0  + (size_t)N_NODES*HID;             // 1.6M f
  float* agg  = h1  + (size_t)N_NODES*HID;             // 1.6M f (f32 aggregation)
  int*  deg   = (int*)(agg + (size_t)N_NODES*HID);     // 50k
  int*  off   = deg + N_NODES;                         // 50k+1 (alloc 50016)
  int*  cursor= off + N_NODES + 16;                    // 50k
  int*  csrs  = cursor + N_NODES;                      // 200k  csr_src
  int*  csre  = csrs + N_EDGES;                        // 200k  csr_eid
  int*  csrd  = csre + N_EDGES;                        // 200k  csr_dst
  unsigned short* w2a = (unsigned short*)(csrd + N_EDGES); // 3*33792 bf16
  unsigned short* w1p = w2a + 3*W2A_L;                 // 3*1024 bf16

  // deg = 0 (stream-ordered fill; capture-safe — the harness's own resets use
  // the same primitive), then the fused independent prelude.
  hipMemsetAsync(deg, 0, (size_t)N_NODES*sizeof(int), stream);
  k_mega<<<MEGA_BLOCKS, 256, 0, stream>>>(ew2, eb2, ew1, ei, x, liw, lib,
                                          w2a, w1p, deg, agg, h0);
  k_scan_one<<<1, 1024, 0, stream>>>(deg, off, cursor);
  k_scatter<<<NTILES, 256, 0, stream>>>(ei, off, cursor, csrs, csre, csrd);

  // L1
  k_msgagg<<<NTILES, 256, 0, stream>>>(h0, ea, w1p, eb1,
      w2a, csrs, csre, csrd, off, agg);
  k_root<<<(N_NODES*8 + 255)/256, 256, 0, stream>>>(agg, off, h0, rw, rb, h1);
  // L2
  k_msgagg<<<NTILES, 256, 0, stream>>>(h1, ea, w1p + 1024, eb1 + HID,
      w2a + (size_t)W2A_L, csrs, csre, csrd, off, agg);
  k_root<<<(N_NODES*8 + 255)/256, 256, 0, stream>>>(agg, off, h1, rw + HID*HID, rb + HID, h0);
  // L3 (root fused into decoder)
  k_msgagg<<<NTILES, 256, 0, stream>>>(h0, ea, w1p + 2048, eb1 + 2*HID,
      w2a + (size_t)2*W2A_L, csrs, csre, csrd, off, agg);
  k_decoder<<<(N_NODES + 255)/256, 256, 0, stream>>>(agg, off, h0,
      rw + 2*HID*HID, rb + 2*HID, low, lob, d1w, d1b, d2w, d2b, out);
}

// Round 5
// 279.813 us; speedup vs baseline: 3.0652x; 1.2623x over previous
//
#include <hip/hip_runtime.h>
#include <hip/hip_bf16.h>
#include <stdint.h>

#define N_NODES 50000
#define N_EDGES 200000
#define NODE_F 64
#define EDGE_F 16
#define HID 32
#define LAT 16
#define W2A_L 33792 // per-layer w2a elements: 33 k-steps * 2 m-tiles * 64 lanes * 8
#define NTILES 782  // (N_EDGES+255)/256
#define MEGA_BLOCKS 1024
#define MEGA_THREADS (MEGA_BLOCKS*256)
#define SCAN_BLOCKS 196   // 196*256 = 50176 >= 50000

typedef __attribute__((ext_vector_type(8))) short short8;   // 8 bf16 = 4 VGPR
typedef __attribute__((ext_vector_type(4))) float f32x4;
typedef __attribute__((ext_vector_type(2))) float f32x2;

static __device__ __forceinline__ unsigned short bfbits(float f) {
  union { __hip_bfloat16 h; unsigned short s; } c; c.h = __float2bfloat16(f); return c.s;
}
// Truncation pack: 1x v_perm_b32. lo16 = top of bits(v.x), hi16 = top of bits(v.y).
static __device__ __forceinline__ unsigned pkt(f32x2 v) {
  return __builtin_amdgcn_perm(__float_as_uint(v.y), __float_as_uint(v.x), 0x07060302u);
}
union AFrag { short8 v; unsigned u[4]; };

// ---- mega prelude: w2a/w1p transpose + hist atomics + lin_in + agg zero ----
// All mutually independent (deg pre-zeroed by hipMemsetAsync before this kernel).
// w2a[l][k][mt][lane][j] = A-frag element A[m = mt*16 + (lane&15)][kk = (lane>>4)*8 + j]
//   where A[m][h] = w2[k][h*32 + m]  (k<32), or b2[h*32 + m] (k==32 bias fold).
__global__ __launch_bounds__(256) void k_mega(
    const float* __restrict__ ew2, const float* __restrict__ eb2,
    const float* __restrict__ ew1,
    const int* __restrict__ ei,
    const float* __restrict__ x, const float* __restrict__ liw,
    const float* __restrict__ lib,
    unsigned short* __restrict__ w2a, unsigned short* __restrict__ w1p,
    int* __restrict__ deg, float* __restrict__ agg, float* __restrict__ h0) {
  __shared__ float Ws[NODE_F*HID];
  __shared__ float bs[HID];
  for (int i = threadIdx.x; i < NODE_F*HID; i += 256) Ws[i] = liw[i];
  if (threadIdx.x < HID) bs[threadIdx.x] = lib[threadIdx.x];
  __syncthreads();
  const int g = blockIdx.x*256 + threadIdx.x;     // 0..262143

  // w2a transpose (bf16 A-frags, bias folded as k=32)
  if (g < 3*W2A_L) {
    int l = g / W2A_L;
    int r = g % W2A_L;
    int k = r >> 10;            // 0..32
    int r2 = r & 1023;
    int mt = r2 >> 9;           // 0..1
    int ln = (r2 >> 3) & 63;
    int j  = r2 & 7;
    int h  = (ln >> 4)*8 + j;   // 0..31
    int m  = mt*16 + (ln & 15); // 0..31
    float v = (k < 32) ? ew2[(size_t)l*32768 + k*1024 + h*32 + m]
                       : eb2[(size_t)l*1024 + h*32 + m];
    w2a[g] = bfbits(v);
  }
  // w1p[l][nt][lane][j] = B-frag element B[k=(lane>>4)*8+j][n=nt*16+(lane&15)]
  if (g < 3*2*64*8) {
    int l2 = g >> 10;
    int r3 = g & 1023;
    int nt = r3 >> 9;
    int ln2 = (r3 >> 3) & 63;
    int j2  = r3 & 7;
    int kgr = ln2 >> 4;
    float w = (kgr < 2) ? ew1[(size_t)l2*512 + (kgr*8 + j2)*32 + nt*16 + (ln2 & 15)] : 0.f;
    w1p[g] = bfbits(w);
  }
  // degree histogram (deg pre-zeroed)
  if (g < N_EDGES) {
    int d = ei[N_EDGES + g];
    d = min(max(d, 0), N_NODES-1);
    atomicAdd(&deg[d], 1);
  }
  // agg zero (layer-1 boundary atomics + zero-degree nodes)
  {
    float4 z4 = make_float4(0.f,0.f,0.f,0.f);
    float4* a4 = (float4*)agg;
    for (int i = g; i < N_NODES*HID/4; i += MEGA_THREADS) a4[i] = z4;
  }
  // lin_in: h0 = relu(x @ W + b)
  for (int t = g; t < N_NODES*HID; t += MEGA_THREADS) {
    int n = t >> 5, o = t & 31;
    const float4* xp = (const float4*)(x + (size_t)n*NODE_F);
    float acc = bs[o];
    #pragma unroll
    for (int j = 0; j < NODE_F/4; j++) {
      float4 v = xp[j];
      acc = fmaf(v.x, Ws[(4*j+0)*HID+o], acc);
      acc = fmaf(v.y, Ws[(4*j+1)*HID+o], acc);
      acc = fmaf(v.z, Ws[(4*j+2)*HID+o], acc);
      acc = fmaf(v.w, Ws[(4*j+3)*HID+o], acc);
    }
    h0[t] = fmaxf(acc, 0.f);
  }
}

// two-level scan (proven fast in R0-R2): per-block Hillis-Steele + in-wave
// block-prefix pass.
__global__ __launch_bounds__(256) void k_scan1(const int* __restrict__ deg,
                                               int* __restrict__ off,
                                               int* __restrict__ bsum) {
  __shared__ int s[256];
  const int tid = threadIdx.x;
  const int t = blockIdx.x*256 + tid;
  int d = (t < N_NODES) ? deg[t] : 0;
  s[tid] = d; __syncthreads();
  int v = d;
  #pragma unroll
  for (int ofs = 1; ofs < 256; ofs <<= 1) {
    int w = (tid >= ofs) ? s[tid-ofs] : 0;
    __syncthreads();
    v += w; s[tid] = v;
    __syncthreads();
  }
  if (t < N_NODES) off[t] = v - d;
  if (tid == 255) bsum[blockIdx.x] = v;
}

__global__ __launch_bounds__(256) void k_scan23(int* __restrict__ off,
                                                const int* __restrict__ bsum,
                                                int* __restrict__ cursor) {
  __shared__ int sPref;
  const int tid = threadIdx.x;
  const int b = blockIdx.x;
  if (tid < 64) {
    int acc = 0;
    for (int i = tid; i < b; i += 64) acc += bsum[i];
    #pragma unroll
    for (int o = 32; o; o >>= 1) acc += __shfl_down(acc, o);
    if (tid == 0) sPref = acc;
  }
  __syncthreads();
  int pref = sPref;
  int t = b*256 + tid;
  if (t < N_NODES) {
    off[t] += pref;
    cursor[t] = 0;
  }
  if (t == 0) off[N_NODES] = N_EDGES;
}

// emits CSR-ordered edge metadata: src node, original edge id, dst node
__global__ void k_scatter(const int* __restrict__ ei, const int* __restrict__ off,
                          int* __restrict__ cursor,
                          int* __restrict__ csr_src, int* __restrict__ csr_eid,
                          int* __restrict__ csr_dst) {
  int t = blockIdx.x*256 + threadIdx.x;
  if (t >= N_EDGES) return;
  int d = ei[N_EDGES + t];
  d = min(max(d, 0), N_NODES-1);
  int s = ei[t];
  s = min(max(s, 0), N_NODES-1);
  int pos = off[d] + atomicAdd(&cursor[d], 1);
  csr_src[pos] = s;
  csr_eid[pos] = t;
  csr_dst[pos] = d;
}

// Fused msg + CSR aggregation (identical to R2). Edges in CSR order; each
// block's 256 edges cover a contiguous destination-node run. Messages land in
// the LDS tile (f32), then block-level run-sum: interior nodes -> direct
// float4 store into agg; boundary nodes -> f32 atomics. agg pre-zeroed.
__global__ __launch_bounds__(256) void k_msgagg(const float* __restrict__ hin,
                                                const float* __restrict__ ea,
                                                const unsigned short* __restrict__ w1pl,
                                                const float* __restrict__ b1,
                                                const unsigned short* __restrict__ w2al,
                                                const int* __restrict__ csr_src,
                                                const int* __restrict__ csr_eid,
                                                const int* __restrict__ csr_dst,
                                                const int* __restrict__ off,
                                                float* __restrict__ agg) {
  __shared__ float sHE[256*33];   // he[e][0..32] then (aliased) msg[e][0..31]; stride 33
  __shared__ int   sSRC[256];
  __shared__ int   sEID[256];
  const int tid = threadIdx.x;
  const int be  = blockIdx.x*256;
  const int wv   = tid >> 6;          // wave 0..3
  const int lane = tid & 63;
  const int nn   = lane & 15;
  const int quad = lane >> 4;
  const int wbase = wv*64;            // this wave's 64 edges (local CSR positions)

  // per-wave staging of src/eid + bias K-row (all lanes)
  {
    int el = wbase + lane;
    int pos = min(be + el, N_EDGES-1);
    sSRC[el] = csr_src[pos];
    sEID[el] = csr_eid[pos];
    sHE[el*33 + 32] = 1.0f;
  }

  // --- he via MFMA: 4 M-tiles x 2 N-halves (wave-internal) ---
  {
    short8 wb0 = *(const short8*)(w1pl + lane*8);         // nt=0
    short8 wb1 = *(const short8*)(w1pl + 512 + lane*8);   // nt=1
    f32x4 z = {0.f,0.f,0.f,0.f};
    float bv0 = b1[nn], bv1 = b1[nn + 16];
    #pragma unroll
    for (int t = 0; t < 4; t++) {
      AFrag a;
      if (quad < 2) {
        int e = sEID[wbase + t*16 + nn];
        const float4* p = (const float4*)(ea + (size_t)e*EDGE_F + quad*8);
        float4 u = p[0], v = p[1];
        a.u[0] = pkt(f32x2{u.x,u.y}); a.u[1] = pkt(f32x2{u.z,u.w});
        a.u[2] = pkt(f32x2{v.x,v.y}); a.u[3] = pkt(f32x2{v.z,v.w});
      } else {
        #pragma unroll
        for (int i = 0; i < 4; i++) a.u[i] = 0u;
      }
      f32x4 h0 = __builtin_amdgcn_mfma_f32_16x16x32_bf16(a.v, wb0, z, 0, 0, 0);
      f32x4 h1 = __builtin_amdgcn_mfma_f32_16x16x32_bf16(a.v, wb1, z, 0, 0, 0);
      #pragma unroll
      for (int r = 0; r < 4; r++) {
        int ro = (wbase + t*16 + quad*4 + r)*33;
        sHE[ro + nn]      = fmaxf(h0[r] + bv0, 0.f);
        sHE[ro + 16 + nn] = fmaxf(h1[r] + bv1, 0.f);
      }
    }
  }
  // no barrier: all sHE producer/consumer pairs so far are wave-internal

  // B-frags: x^T per tile, packed ONCE (lane: edge=nn, k=h=quad*8+j)
  short8 bx[4];
  #pragma unroll
  for (int t = 0; t < 4; t++) {
    int si = sSRC[wbase + t*16 + nn];
    const float4* p = (const float4*)(hin + (size_t)si*HID + quad*8);
    float4 a = p[0], b = p[1];
    AFrag f;
    f.u[0] = pkt(f32x2{a.x,a.y}); f.u[1] = pkt(f32x2{a.z,a.w});
    f.u[2] = pkt(f32x2{b.x,b.y}); f.u[3] = pkt(f32x2{b.z,b.w});
    bx[t] = f.v;
  }

  f32x4 c0[4], c1[4];
  #pragma unroll
  for (int t = 0; t < 4; t++) { c0[t] = f32x4{0.f,0.f,0.f,0.f}; c1[t] = c0[t]; }
  const f32x4 zz = {0.f,0.f,0.f,0.f};

  const unsigned short* ap = w2al + (unsigned)lane*8;   // [k][mt][lane][8]
  const float* heR[4];
  #pragma unroll
  for (int t = 0; t < 4; t++) heR[t] = sHE + (wbase + t*16 + nn)*33;

  // depth-3 pipeline slots: A-frags (W_k^T, both M-tiles) + he scalars
  short8 sa0[3], sa1[3];
  float  sh[3][4];
  #pragma unroll
  for (int j = 0; j < 3; j++) {
    sa0[j] = *(const short8*)(ap + j*1024);
    sa1[j] = *(const short8*)(ap + j*1024 + 512);
    #pragma unroll
    for (int t = 0; t < 4; t++) sh[j][t] = heR[t][j];
  }

  #pragma unroll 1
  for (int base = 0; base < 30; base += 3) {
    #pragma unroll
    for (int j = 0; j < 3; j++) {
      const int kk = base + j;
      short8 a0 = sa0[j], a1 = sa1[j];
      #pragma unroll
      for (int t = 0; t < 4; t++) {
        f32x4 u0 = __builtin_amdgcn_mfma_f32_16x16x32_bf16(a0, bx[t], zz, 0, 0, 0);
        f32x4 u1 = __builtin_amdgcn_mfma_f32_16x16x32_bf16(a1, bx[t], zz, 0, 0, 0);
        float hk = sh[j][t];
        #pragma unroll
        for (int r = 0; r < 4; r++) {
          c0[t][r] = fmaf(hk, u0[r], c0[t][r]);
          c1[t][r] = fmaf(hk, u1[r], c1[t][r]);
        }
      }
      sa0[j] = *(const short8*)(ap + (kk+3)*1024);
      sa1[j] = *(const short8*)(ap + (kk+3)*1024 + 512);
      #pragma unroll
      for (int t = 0; t < 4; t++) sh[j][t] = heR[t][kk+3];
    }
  }
  #pragma unroll
  for (int j = 0; j < 3; j++) {
    short8 a0 = sa0[j], a1 = sa1[j];
    #pragma unroll
    for (int t = 0; t < 4; t++) {
      f32x4 u0 = __builtin_amdgcn_mfma_f32_16x16x32_bf16(a0, bx[t], zz, 0, 0, 0);
      f32x4 u1 = __builtin_amdgcn_mfma_f32_16x16x32_bf16(a1, bx[t], zz, 0, 0, 0);
      float hk = sh[j][t];
      #pragma unroll
      for (int r = 0; r < 4; r++) {
        c0[t][r] = fmaf(hk, u0[r], c0[t][r]);
        c1[t][r] = fmaf(hk, u1[r], c1[t][r]);
      }
    }
  }

  // msg -> LDS, aliasing this wave's own sHE rows (wave-internal WAR)
  #pragma unroll
  for (int t = 0; t < 4; t++) {
    int ro = (wbase + t*16 + nn)*33 + quad*4;
    sHE[ro + 0]  = c0[t][0]; sHE[ro + 1]  = c0[t][1];
    sHE[ro + 2]  = c0[t][2]; sHE[ro + 3]  = c0[t][3];
    sHE[ro + 16] = c1[t][0]; sHE[ro + 17] = c1[t][1];
    sHE[ro + 18] = c1[t][2]; sHE[ro + 19] = c1[t][3];
  }
  __syncthreads();

  // block-level CSR-run aggregation from the LDS msg tile
  const int s    = be;
  const int wend = s + 256;
  const int nF = csr_dst[min(s,       N_EDGES-1)];
  const int nL = csr_dst[min(s + 255, N_EDGES-1)];
  for (int basei = 0; basei <= nL - nF; basei += 32) {
    int idx = basei + (tid >> 3);
    int n = nF + idx;
    if (n <= nL) {
      int oc = tid & 7;
      int s0 = off[n], s1 = off[n+1];
      int lo = max(s0, s) - s;
      int hi = min(s1, wend) - s;
      float a0 = 0.f, a1 = 0.f, a2 = 0.f, a3 = 0.f;
      for (int j = lo; j < hi; j++) {
        const float* row = sHE + j*33 + oc*4;
        a0 += row[0]; a1 += row[1]; a2 += row[2]; a3 += row[3];
      }
      float* dst = agg + (size_t)n*HID + oc*4;
      if (s0 >= s && s1 <= wend) {
        *(float4*)dst = make_float4(a0, a1, a2, a3);
      } else {
        atomicAdd(dst + 0, a0); atomicAdd(dst + 1, a1);
        atomicAdd(dst + 2, a2); atomicAdd(dst + 3, a3);
      }
    }
  }
}

// hout = relu( agg/deg + hin @ root_w + root_b ); re-zeroes agg for next layer.
__global__ void k_root(float* __restrict__ agg,
                       const int* __restrict__ off,
                       const float* __restrict__ hin,
                       const float* __restrict__ rw,
                       const float* __restrict__ rb,
                       float* __restrict__ hout) {
  __shared__ float rws[HID*HID];
  __shared__ float rbs[HID];
  for (int i = threadIdx.x; i < HID*HID; i += 256) rws[i] = rw[i];
  if (threadIdx.x < HID) rbs[threadIdx.x] = rb[threadIdx.x];
  __syncthreads();
  int t = blockIdx.x*256 + threadIdx.x;
  if (t >= N_NODES*8) return;
  int n = t >> 3, oc = t & 7;
  float4* ap = (float4*)(agg + (size_t)n*HID);
  float4 av = ap[oc];
  float inv = 1.f / fmaxf((float)(off[n+1] - off[n]), 1.f);
  float a0 = fmaf(av.x, inv, rbs[oc*4+0]);
  float a1 = fmaf(av.y, inv, rbs[oc*4+1]);
  float a2 = fmaf(av.z, inv, rbs[oc*4+2]);
  float a3 = fmaf(av.w, inv, rbs[oc*4+3]);
  const float4* hp = (const float4*)(hin + (size_t)n*HID);
  #pragma unroll
  for (int jq = 0; jq < 8; jq++) {
    float4 hv = hp[jq];
    #pragma unroll
    for (int c = 0; c < 4; c++) {
      int j = jq*4 + c;
      float h = (c==0)?hv.x:(c==1)?hv.y:(c==2)?hv.z:hv.w;
      const float4* rp = (const float4*)(rws + j*HID + oc*4);
      float4 r = rp[0];
      a0 = fmaf(h, r.x, a0);
      a1 = fmaf(h, r.y, a1);
      a2 = fmaf(h, r.z, a2);
      a3 = fmaf(h, r.w, a3);
    }
  }
  ((float4*)(hout + (size_t)n*HID))[oc] =
      make_float4(fmaxf(a0,0.f), fmaxf(a1,0.f), fmaxf(a2,0.f), fmaxf(a3,0.f));
  ap[oc] = make_float4(0.f, 0.f, 0.f, 0.f);   // ready for next layer
}

// layer-3 root fused in: hr = relu(agg/deg + h@rw + rb), then
// out = (relu((hr@lo_w+lo_b)@d1_w+d1_b))@d2_w+d2_b   (no relu on z)
__global__ void k_decoder(const float* __restrict__ agg,
                          const int* __restrict__ off,
                          const float* __restrict__ h,
                          const float* __restrict__ rw, const float* __restrict__ rb,
                          const float* __restrict__ lo_w, const float* __restrict__ lo_b,
                          const float* __restrict__ d1_w, const float* __restrict__ d1_b,
                          const float* __restrict__ d2_w, const float* __restrict__ d2_b,
                          float* __restrict__ out) {
  __shared__ float rws[HID*HID], rbs[HID];
  __shared__ float lows[HID*LAT], lobs[LAT], d1s[LAT*HID], d1bs[HID], d2s[HID*NODE_F], d2bs[NODE_F];
  for (int i = threadIdx.x; i < HID*HID; i += 256) rws[i] = rw[i];
  for (int i = threadIdx.x; i < HID; i += 256) rbs[i] = rb[i];
  for (int i = threadIdx.x; i < HID*LAT; i += 256) lows[i] = lo_w[i];
  for (int i = threadIdx.x; i < LAT; i += 256) lobs[i] = lo_b[i];
  for (int i = threadIdx.x; i < LAT*HID; i += 256) d1s[i] = d1_w[i];
  for (int i = threadIdx.x; i < HID; i += 256) d1bs[i] = d1_b[i];
  for (int i = threadIdx.x; i < HID*NODE_F; i += 256) d2s[i] = d2_w[i];
  for (int i = threadIdx.x; i < NODE_F; i += 256) d2bs[i] = d2_b[i];
  __syncthreads();
  int n = blockIdx.x*256 + threadIdx.x;
  if (n >= N_NODES) return;
  float hv[HID], av[HID];
  const float4* hp = (const float4*)(h + (size_t)n*HID);
  const float4* ap = (const float4*)(agg + (size_t)n*HID);
  #pragma unroll
  for (int i = 0; i < HID/4; i++) {
    float4 v = hp[i]; hv[4*i]=v.x; hv[4*i+1]=v.y; hv[4*i+2]=v.z; hv[4*i+3]=v.w;
    float4 a = ap[i]; av[4*i]=a.x; av[4*i+1]=a.y; av[4*i+2]=a.z; av[4*i+3]=a.w;
  }
  float inv = 1.f / fmaxf((float)(off[n+1] - off[n]), 1.f);
  float hr[HID];
  #pragma unroll 4
  for (int o = 0; o < HID; o++) {
    float a = fmaf(av[o], inv, rbs[o]);
    #pragma unroll
    for (int j = 0; j < HID; j++) a = fmaf(hv[j], rws[j*HID+o], a);
    hr[o] = fmaxf(a, 0.f);
  }
  float z[LAT];
  #pragma unroll
  for (int o = 0; o < LAT; o++) {
    float a = lobs[o];
    #pragma unroll
    for (int j = 0; j < HID; j++) a = fmaf(hr[j], lows[j*LAT+o], a);
    z[o] = a;
  }
  float d[HID];
  #pragma unroll
  for (int o = 0; o < HID; o++) {
    float a = d1bs[o];
    #pragma unroll
    for (int j = 0; j < LAT; j++) a = fmaf(z[j], d1s[j*HID+o], a);
    d[o] = fmaxf(a, 0.f);
  }
  float* op = out + (size_t)n*NODE_F;
  #pragma unroll 8
  for (int o = 0; o < NODE_F; o++) {
    float a = d2bs[o];
    #pragma unroll
    for (int j = 0; j < HID; j++) a = fmaf(d[j], d2s[j*NODE_F+o], a);
    op[o] = a;
  }
}

extern "C" void kernel_launch(void* const* d_in, const int* in_sizes, int n_in,
                              void* d_out, int out_size, void* d_ws, size_t ws_size,
                              hipStream_t stream) {
  const float* x   = (const float*)d_in[0];
  const int*   ei  = (const int*)d_in[1];
  const float* ea  = (const float*)d_in[2];
  const float* liw = (const float*)d_in[3];
  const float* lib = (const float*)d_in[4];
  const float* ew1 = (const float*)d_in[5];
  const float* eb1 = (const float*)d_in[6];
  const float* ew2 = (const float*)d_in[7];
  const float* eb2 = (const float*)d_in[8];
  const float* rw  = (const float*)d_in[9];
  const float* rb  = (const float*)d_in[10];
  const float* low = (const float*)d_in[11];
  const float* lob = (const float*)d_in[12];
  const float* d1w = (const float*)d_in[13];
  const float* d1b = (const float*)d_in[14];
  const float* d2w = (const float*)d_in[15];
  const float* d2b = (const float*)d_in[16];
  float* out = (float*)d_out;

  float* h0   = (float*)d_ws;                          // 1.6M f
  float* h1   = h0  + (size_t)N_NODES*HID;             // 1.6M f
  float* agg  = h1  + (size_t)N_NODES*HID;             // 1.6M f (f32 aggregation)
  int*  deg   = (int*)(agg + (size_t)N_NODES*HID);     // 50k
  int*  off   = deg + N_NODES;                         // 50k+1 (alloc 50016)
  int*  cursor= off + N_NODES + 16;                    // 50k
  int*  csrs  = cursor + N_NODES;                      // 200k  csr_src
  int*  csre  = csrs + N_EDGES;                        // 200k  csr_eid
  int*  csrd  = csre + N_EDGES;                        // 200k  csr_dst
  int*  bsum  = csrd + N_EDGES;                        // 256
  unsigned short* w2a = (unsigned short*)(bsum + 256); // 3*33792 bf16
  unsigned short* w1p = w2a + 3*W2A_L;                 // 3*1024 bf16

  // deg = 0 (stream-ordered fill, capture-safe), then fused independent prelude.
  hipMemsetAsync(deg, 0, (size_t)N_NODES*sizeof(int), stream);
  k_mega<<<MEGA_BLOCKS, 256, 0, stream>>>(ew2, eb2, ew1, ei, x, liw, lib,
                                          w2a, w1p, deg, agg, h0);
  k_scan1<<<SCAN_BLOCKS, 256, 0, stream>>>(deg, off, bsum);
  k_scan23<<<SCAN_BLOCKS, 256, 0, stream>>>(off, bsum, cursor);
  k_scatter<<<NTILES, 256, 0, stream>>>(ei, off, cursor, csrs, csre, csrd);

  // L1
  k_msgagg<<<NTILES, 256, 0, stream>>>(h0, ea, w1p, eb1,
      w2a, csrs, csre, csrd, off, agg);
  k_root<<<(N_NODES*8 + 255)/256, 256, 0, stream>>>(agg, off, h0, rw, rb, h1);
  // L2
  k_msgagg<<<NTILES, 256, 0, stream>>>(h1, ea, w1p + 1024, eb1 + HID,
      w2a + (size_t)W2A_L, csrs, csre, csrd, off, agg);
  k_root<<<(N_NODES*8 + 255)/256, 256, 0, stream>>>(agg, off, h1, rw + HID*HID, rb + HID, h0);
  // L3 (root fused into decoder)
  k_msgagg<<<NTILES, 256, 0, stream>>>(h0, ea, w1p + 2048, eb1 + 2*HID,
      w2a + (size_t)2*W2A_L, csrs, csre, csrd, off, agg);
  k_decoder<<<(N_NODES + 255)/256, 256, 0, stream>>>(agg, off, h0,
      rw + 2*HID*HID, rb + 2*HID, low, lob, d1w, d1b, d2w, d2b, out);
}